// Round 1
// baseline (1595.060 us; speedup 1.0000x reference)
//
#include <hip/hip_runtime.h>
#include <math.h>

namespace {
constexpr int N = 1000000;
constexpr int E = 1000000;
constexpr int C = 64;            // poss_node cols; poss_edge has C+1 = 65 cols
constexpr int NODE_BLOCKS = 1024;
constexpr int EDGE_BLOCKS = 2048;
constexpr int BLOCK = 256;
constexpr double SEMI_LAMBDA = 0.5;
constexpr double EDGE_LAMBDA = 1.0;
}

__device__ __forceinline__ float waveReduceSum(float v) {
#pragma unroll
    for (int off = 32; off > 0; off >>= 1) v += __shfl_down(v, off, 64);
    return v;
}

// ---------------- node loss: -sum(mask * log p[i, gt[i]]) / sum(mask) ----------
__global__ __launch_bounds__(BLOCK) void node_kernel(
    const float* __restrict__ poss_node,
    const int* __restrict__ gt,
    const int* __restrict__ mask,
    float* __restrict__ partials)   // [2][NODE_BLOCKS]
{
    float lsum = 0.f, cnt = 0.f;
    for (int i = blockIdx.x * BLOCK + threadIdx.x; i < N; i += NODE_BLOCKS * BLOCK) {
        if (mask[i] != 0) {
            lsum += logf(poss_node[(size_t)i * C + gt[i]]);
            cnt += 1.f;
        }
    }
    __shared__ float s0[BLOCK / 64], s1[BLOCK / 64];
    lsum = waveReduceSum(lsum);
    cnt  = waveReduceSum(cnt);
    const int lane = threadIdx.x & 63, wv = threadIdx.x >> 6;
    if (lane == 0) { s0[wv] = lsum; s1[wv] = cnt; }
    __syncthreads();
    if (threadIdx.x == 0) {
        float a = 0.f, b = 0.f;
#pragma unroll
        for (int w = 0; w < BLOCK / 64; ++w) { a += s0[w]; b += s1[w]; }
        partials[blockIdx.x]               = a;
        partials[NODE_BLOCKS + blockIdx.x] = b;
    }
}

// ---------------- edge: semi (s1, sqdiff) + label-pair log terms ---------------
__global__ __launch_bounds__(BLOCK) void edge_kernel(
    const float* __restrict__ poss_edge,
    const int* __restrict__ gt,
    const int* __restrict__ mask,
    const int* __restrict__ edges,
    float* __restrict__ partials)   // [4][EDGE_BLOCKS]: s1, sqdiff, pos_logs, label_cnt
{
    float s1 = 0.f, sq = 0.f, pos = 0.f, lcnt = 0.f;
    for (int e = blockIdx.x * BLOCK + threadIdx.x; e < E; e += EDGE_BLOCKS * BLOCK) {
        const int e0 = edges[2 * e];
        const int e1 = edges[2 * e + 1];

        const float* __restrict__ re = poss_edge + (size_t)e  * (C + 1);
        const float* __restrict__ ra = poss_edge + (size_t)e0 * (C + 1);
        const float* __restrict__ rb = poss_edge + (size_t)e1 * (C + 1);

        const float p_last = re[C];
        s1 += 1.f - p_last;           // stop_gradient(intrust) forward value

        float acc = 0.f;
#pragma unroll 4
        for (int c = 0; c < C + 1; ++c) {
            const float d = ra[c] - rb[c];
            acc = fmaf(d, d, acc);
        }
        sq += acc;

        const int m0 = (mask[e0] != 0);
        const int m1 = (mask[e1] != 0);
        if (m0 | m1) {
            lcnt += 1.f;
            const int g0 = gt[e0];
            const int g1 = gt[e1];
            if (m0 & m1) {
                pos += (g0 == g1) ? logf(re[g0]) : logf(p_last);
            } else if (m0) {
                pos += logf(p_last + re[g0]);
            } else {
                pos += logf(p_last + re[g1]);
            }
        }
    }
    __shared__ float s[4][BLOCK / 64];
    s1   = waveReduceSum(s1);
    sq   = waveReduceSum(sq);
    pos  = waveReduceSum(pos);
    lcnt = waveReduceSum(lcnt);
    const int lane = threadIdx.x & 63, wv = threadIdx.x >> 6;
    if (lane == 0) { s[0][wv] = s1; s[1][wv] = sq; s[2][wv] = pos; s[3][wv] = lcnt; }
    __syncthreads();
    if (threadIdx.x == 0) {
        float a = 0.f, b = 0.f, c = 0.f, d = 0.f;
#pragma unroll
        for (int w = 0; w < BLOCK / 64; ++w) {
            a += s[0][w]; b += s[1][w]; c += s[2][w]; d += s[3][w];
        }
        partials[0 * EDGE_BLOCKS + blockIdx.x] = a;
        partials[1 * EDGE_BLOCKS + blockIdx.x] = b;
        partials[2 * EDGE_BLOCKS + blockIdx.x] = c;
        partials[3 * EDGE_BLOCKS + blockIdx.x] = d;
    }
}

// ---------------- final combine in fp64 ----------------------------------------
__global__ __launch_bounds__(BLOCK) void finalize_kernel(
    const float* __restrict__ node_partials,
    const float* __restrict__ edge_partials,
    float* __restrict__ out)
{
    double a0 = 0, a1 = 0, a2 = 0, a3 = 0, a4 = 0, a5 = 0;
    for (int i = threadIdx.x; i < NODE_BLOCKS; i += BLOCK) {
        a0 += (double)node_partials[i];
        a1 += (double)node_partials[NODE_BLOCKS + i];
    }
    for (int i = threadIdx.x; i < EDGE_BLOCKS; i += BLOCK) {
        a2 += (double)edge_partials[0 * EDGE_BLOCKS + i];
        a3 += (double)edge_partials[1 * EDGE_BLOCKS + i];
        a4 += (double)edge_partials[2 * EDGE_BLOCKS + i];
        a5 += (double)edge_partials[3 * EDGE_BLOCKS + i];
    }
#pragma unroll
    for (int off = 32; off > 0; off >>= 1) {
        a0 += __shfl_down(a0, off, 64);
        a1 += __shfl_down(a1, off, 64);
        a2 += __shfl_down(a2, off, 64);
        a3 += __shfl_down(a3, off, 64);
        a4 += __shfl_down(a4, off, 64);
        a5 += __shfl_down(a5, off, 64);
    }
    __shared__ double sd[6][BLOCK / 64];
    const int lane = threadIdx.x & 63, wv = threadIdx.x >> 6;
    if (lane == 0) {
        sd[0][wv] = a0; sd[1][wv] = a1; sd[2][wv] = a2;
        sd[3][wv] = a3; sd[4][wv] = a4; sd[5][wv] = a5;
    }
    __syncthreads();
    if (threadIdx.x == 0) {
        double t[6];
#pragma unroll
        for (int k = 0; k < 6; ++k) {
            double v = 0;
#pragma unroll
            for (int w = 0; w < BLOCK / 64; ++w) v += sd[k][w];
            t[k] = v;
        }
        const double logp_sum  = t[0];
        const double mask_cnt  = t[1];
        const double s1_sum    = t[2];
        const double sq_sum    = t[3];
        const double pos_sum   = t[4];
        const double label_cnt = t[5];

        const double loss      = -logp_sum / mask_cnt;
        const double semi      = SEMI_LAMBDA * s1_sum * sq_sum;
        const double raw       = -pos_sum;
        const double edge_loss = raw * (EDGE_LAMBDA * EDGE_LAMBDA) / (label_cnt * label_cnt);

        out[0] = (float)(loss + semi + edge_loss);
    }
}

extern "C" void kernel_launch(void* const* d_in, const int* in_sizes, int n_in,
                              void* d_out, int out_size, void* d_ws, size_t ws_size,
                              hipStream_t stream) {
    const float* poss_node = (const float*)d_in[0];
    const float* poss_edge = (const float*)d_in[1];
    const int*   gt        = (const int*)d_in[2];
    const int*   mask      = (const int*)d_in[3];
    const int*   edges     = (const int*)d_in[4];
    float*       out       = (float*)d_out;

    float* node_partials = (float*)d_ws;                         // 2 * NODE_BLOCKS floats
    float* edge_partials = node_partials + 2 * NODE_BLOCKS;      // 4 * EDGE_BLOCKS floats

    node_kernel<<<NODE_BLOCKS, BLOCK, 0, stream>>>(poss_node, gt, mask, node_partials);
    edge_kernel<<<EDGE_BLOCKS, BLOCK, 0, stream>>>(poss_edge, gt, mask, edges, edge_partials);
    finalize_kernel<<<1, BLOCK, 0, stream>>>(node_partials, edge_partials, out);
}

// Round 3
// 585.205 us; speedup vs baseline: 2.7256x; 2.7256x over previous
//
#include <hip/hip_runtime.h>
#include <math.h>

namespace {
constexpr int N = 1000000;
constexpr int E = 1000000;
constexpr int C = 64;            // poss_node cols; poss_edge has C+1 = 65 cols
constexpr int NODE_BLOCKS = 1024;   // R1-proven ws layout: 2*1024 + 4*2048 floats = 40960 B
constexpr int EDGE_BLOCKS = 2048;
constexpr int BLOCK = 256;
constexpr int GROUPS_PER_BLOCK = BLOCK / 16;                  // 16 groups of 16 lanes
constexpr int TOTAL_GROUPS = EDGE_BLOCKS * GROUPS_PER_BLOCK;  // 32768
constexpr double SEMI_LAMBDA = 0.5;
constexpr double EDGE_LAMBDA = 1.0;
}

__device__ __forceinline__ float waveReduceSum(float v) {
#pragma unroll
    for (int off = 32; off > 0; off >>= 1) v += __shfl_down(v, off, 64);
    return v;
}

// ---------------- node loss: -sum(mask * log p[i, gt[i]]) / sum(mask) ----------
__global__ __launch_bounds__(BLOCK) void node_kernel(
    const float* __restrict__ poss_node,
    const int* __restrict__ gt,
    const int* __restrict__ mask,
    float* __restrict__ partials)   // [2][NODE_BLOCKS]
{
    float lsum = 0.f, cnt = 0.f;
    for (int i = blockIdx.x * BLOCK + threadIdx.x; i < N; i += NODE_BLOCKS * BLOCK) {
        if (mask[i] != 0) {
            lsum += logf(poss_node[(size_t)i * C + gt[i]]);
            cnt += 1.f;
        }
    }
    __shared__ float s0[BLOCK / 64], s1[BLOCK / 64];
    lsum = waveReduceSum(lsum);
    cnt  = waveReduceSum(cnt);
    const int lane = threadIdx.x & 63, wv = threadIdx.x >> 6;
    if (lane == 0) { s0[wv] = lsum; s1[wv] = cnt; }
    __syncthreads();
    if (threadIdx.x == 0) {
        float a = 0.f, b = 0.f;
#pragma unroll
        for (int w = 0; w < BLOCK / 64; ++w) { a += s0[w]; b += s1[w]; }
        partials[blockIdx.x]               = a;
        partials[NODE_BLOCKS + blockIdx.x] = b;
    }
}

// ---------------- edge: 16-lane group per edge, coalesced row reads ------------
__global__ __launch_bounds__(BLOCK) void edge_kernel(
    const float* __restrict__ poss_edge,
    const int* __restrict__ gt,
    const int* __restrict__ mask,
    const int* __restrict__ edges,
    float* __restrict__ partials)   // [4][EDGE_BLOCKS]: s1, sqdiff, pos_logs, label_cnt
{
    const int t   = threadIdx.x & 15;                       // sub-lane in group
    const int grp = threadIdx.x >> 4;                       // group in block
    const int globalGroup = blockIdx.x * GROUPS_PER_BLOCK + grp;

    float s1 = 0.f, sq = 0.f, pos = 0.f, lcnt = 0.f;

    for (int e = globalGroup; e < E; e += TOTAL_GROUPS) {
        const int2 ep = *(const int2*)(edges + 2 * (size_t)e);
        const int e0 = ep.x, e1 = ep.y;

        const float* __restrict__ ra = poss_edge + (size_t)e0 * (C + 1);
        const float* __restrict__ rb = poss_edge + (size_t)e1 * (C + 1);
        const float* __restrict__ re = poss_edge + (size_t)e  * (C + 1);

        // --- sqdiff: lane t covers columns t, t+16, t+32, t+48 (t==0 adds col 64)
        const float a0 = ra[t], a1 = ra[t + 16], a2 = ra[t + 32], a3 = ra[t + 48];
        const float b0 = rb[t], b1 = rb[t + 16], b2 = rb[t + 32], b3 = rb[t + 48];
        const float d0 = a0 - b0, d1 = a1 - b1, d2 = a2 - b2, d3 = a3 - b3;
        float acc = fmaf(d0, d0, fmaf(d1, d1, fmaf(d2, d2, d3 * d3)));
        if (t == 0) {
            const float dl = ra[C] - rb[C];
            acc = fmaf(dl, dl, acc);
        }
        sq += acc;

        // --- per-edge scalar terms (group-uniform; broadcast loads)
        const float p_last = re[C];
        const int m0 = (mask[e0] != 0);
        const int m1 = (mask[e1] != 0);
        if (m0 | m1) {
            const int g0 = gt[e0];
            const int g1 = gt[e1];
            float contrib;
            if (m0 & m1) {
                contrib = (g0 == g1) ? logf(re[g0]) : logf(p_last);
            } else if (m0) {
                contrib = logf(p_last + re[g0]);
            } else {
                contrib = logf(p_last + re[g1]);
            }
            if (t == 0) { pos += contrib; lcnt += 1.f; }
        }
        if (t == 0) s1 += 1.f - p_last;
    }

    __shared__ float s[4][BLOCK / 64];
    s1   = waveReduceSum(s1);
    sq   = waveReduceSum(sq);
    pos  = waveReduceSum(pos);
    lcnt = waveReduceSum(lcnt);
    const int lane = threadIdx.x & 63, wv = threadIdx.x >> 6;
    if (lane == 0) { s[0][wv] = s1; s[1][wv] = sq; s[2][wv] = pos; s[3][wv] = lcnt; }
    __syncthreads();
    if (threadIdx.x == 0) {
        float a = 0.f, b = 0.f, c = 0.f, d = 0.f;
#pragma unroll
        for (int w = 0; w < BLOCK / 64; ++w) {
            a += s[0][w]; b += s[1][w]; c += s[2][w]; d += s[3][w];
        }
        partials[0 * EDGE_BLOCKS + blockIdx.x] = a;
        partials[1 * EDGE_BLOCKS + blockIdx.x] = b;
        partials[2 * EDGE_BLOCKS + blockIdx.x] = c;
        partials[3 * EDGE_BLOCKS + blockIdx.x] = d;
    }
}

// ---------------- final combine in fp64 ----------------------------------------
__global__ __launch_bounds__(BLOCK) void finalize_kernel(
    const float* __restrict__ node_partials,
    const float* __restrict__ edge_partials,
    float* __restrict__ out)
{
    double a0 = 0, a1 = 0, a2 = 0, a3 = 0, a4 = 0, a5 = 0;
    for (int i = threadIdx.x; i < NODE_BLOCKS; i += BLOCK) {
        a0 += (double)node_partials[i];
        a1 += (double)node_partials[NODE_BLOCKS + i];
    }
    for (int i = threadIdx.x; i < EDGE_BLOCKS; i += BLOCK) {
        a2 += (double)edge_partials[0 * EDGE_BLOCKS + i];
        a3 += (double)edge_partials[1 * EDGE_BLOCKS + i];
        a4 += (double)edge_partials[2 * EDGE_BLOCKS + i];
        a5 += (double)edge_partials[3 * EDGE_BLOCKS + i];
    }
#pragma unroll
    for (int off = 32; off > 0; off >>= 1) {
        a0 += __shfl_down(a0, off, 64);
        a1 += __shfl_down(a1, off, 64);
        a2 += __shfl_down(a2, off, 64);
        a3 += __shfl_down(a3, off, 64);
        a4 += __shfl_down(a4, off, 64);
        a5 += __shfl_down(a5, off, 64);
    }
    __shared__ double sd[6][BLOCK / 64];
    const int lane = threadIdx.x & 63, wv = threadIdx.x >> 6;
    if (lane == 0) {
        sd[0][wv] = a0; sd[1][wv] = a1; sd[2][wv] = a2;
        sd[3][wv] = a3; sd[4][wv] = a4; sd[5][wv] = a5;
    }
    __syncthreads();
    if (threadIdx.x == 0) {
        double t[6];
#pragma unroll
        for (int k = 0; k < 6; ++k) {
            double v = 0;
#pragma unroll
            for (int w = 0; w < BLOCK / 64; ++w) v += sd[k][w];
            t[k] = v;
        }
        const double logp_sum  = t[0];
        const double mask_cnt  = t[1];
        const double s1_sum    = t[2];
        const double sq_sum    = t[3];
        const double pos_sum   = t[4];
        const double label_cnt = t[5];

        const double loss      = -logp_sum / mask_cnt;
        const double semi      = SEMI_LAMBDA * s1_sum * sq_sum;
        const double raw       = -pos_sum;
        const double edge_loss = raw * (EDGE_LAMBDA * EDGE_LAMBDA) / (label_cnt * label_cnt);

        out[0] = (float)(loss + semi + edge_loss);
    }
}

extern "C" void kernel_launch(void* const* d_in, const int* in_sizes, int n_in,
                              void* d_out, int out_size, void* d_ws, size_t ws_size,
                              hipStream_t stream) {
    const float* poss_node = (const float*)d_in[0];
    const float* poss_edge = (const float*)d_in[1];
    const int*   gt        = (const int*)d_in[2];
    const int*   mask      = (const int*)d_in[3];
    const int*   edges     = (const int*)d_in[4];
    float*       out       = (float*)d_out;

    float* node_partials = (float*)d_ws;                         // 2 * NODE_BLOCKS floats
    float* edge_partials = node_partials + 2 * NODE_BLOCKS;      // 4 * EDGE_BLOCKS floats

    node_kernel<<<NODE_BLOCKS, BLOCK, 0, stream>>>(poss_node, gt, mask, node_partials);
    edge_kernel<<<EDGE_BLOCKS, BLOCK, 0, stream>>>(poss_edge, gt, mask, edges, edge_partials);
    finalize_kernel<<<1, BLOCK, 0, stream>>>(node_partials, edge_partials, out);
}